// Round 1
// baseline (983.175 us; speedup 1.0000x reference)
//
#include <hip/hip_runtime.h>
#include <hip/hip_bf16.h>

// JointNetwork: out[b,t,u,v] = sum_h tanh(E[bt,h]+D[bu,h]) * W_joint[v,h] + b_joint[v]
// E = enc_out @ W_enc^T + b_enc ; D = dec_out @ W_dec^T + b_dec
// B=4 T=256 U=128 H=512 V=1024.
// Strategy: phase-1 fp32 vector GEMMs (tiny), phase-2 bf16 MFMA 16x16x32 with
// J-panel [128x512] bf16 resident in LDS per (b,t) block (tanh computed once).
// Workspace layout (needs 6 MB of d_ws):
//   [0,1MB)   WencT fp32 [512][512]  (W_enc transposed)
//   [1,2MB)   WdecT fp32 [512][512]
//   [2,3MB)   Wjb   bf16 [1024][512] (W_joint converted)
//   [3,5MB)   E     fp32 [1024][512]
//   [5,6MB)   D     fp32 [512][512]

typedef float floatx4 __attribute__((ext_vector_type(4)));
typedef __bf16 bf16x8 __attribute__((ext_vector_type(8)));
typedef unsigned short ushort8v __attribute__((ext_vector_type(8)));

__device__ __forceinline__ unsigned short f2bf(float f) {
  // RNE float->bf16 (inputs are finite, no NaN handling needed)
  unsigned int u = __builtin_bit_cast(unsigned int, f);
  u += 0x7fffu + ((u >> 16) & 1u);
  return (unsigned short)(u >> 16);
}

__device__ __forceinline__ float fast_tanh(float x) {
  // tanh(x) = 1 - 2/(exp(2x)+1); exp->inf => 1, exp->0 => -1 (branch-free)
  float z = __expf(2.0f * x);
  return 1.0f - __fdividef(2.0f, z + 1.0f);
}

// ---------------------------------------------------------------- prep ------
// grid 1024 x 256: blocks [0,256) transpose W_enc, [256,512) transpose W_dec,
// [512,1024) convert W_joint fp32 -> bf16.
__global__ void prep_kernel(const float* __restrict__ W_enc,
                            const float* __restrict__ W_dec,
                            const float* __restrict__ W_joint,
                            float* __restrict__ WencT, float* __restrict__ WdecT,
                            unsigned short* __restrict__ Wjb) {
  __shared__ float tile[32][33];
  const int bid = blockIdx.x, t = threadIdx.x;
  if (bid < 512) {
    const float* src = (bid < 256) ? W_enc : W_dec;
    float* dst = (bid < 256) ? WencT : WdecT;
    const int tb = bid & 255;
    const int tr = (tb >> 4) * 32, tc = (tb & 15) * 32;
    const int tx = t & 31, ty = t >> 5;
#pragma unroll
    for (int i = 0; i < 4; ++i) {
      int r = ty + i * 8;
      tile[r][tx] = src[(tr + r) * 512 + tc + tx];
    }
    __syncthreads();
#pragma unroll
    for (int i = 0; i < 4; ++i) {
      int r = ty + i * 8;
      dst[(tc + r) * 512 + tr + tx] = tile[tx][r];
    }
  } else {
    const int cid = bid - 512;
    const int base = (cid * 256 + t) * 4;
    float4 v = *(const float4*)&W_joint[base];
    ushort4 o;
    o.x = f2bf(v.x); o.y = f2bf(v.y); o.z = f2bf(v.z); o.w = f2bf(v.w);
    *(ushort4*)&Wjb[base] = o;
  }
}

// ---------------------------------------------------------------- proj ------
// grid 192 x 256: blocks [0,128) compute E rows (8/block), [128,192) D rows.
// out[m][n] = sum_k X[m][k] * Wt[k][n] + bias[n]   (Wt = W^T, coalesced over n)
__global__ void proj_kernel(const float* __restrict__ enc,
                            const float* __restrict__ dec,
                            const float* __restrict__ WencT,
                            const float* __restrict__ WdecT,
                            const float* __restrict__ b_enc,
                            const float* __restrict__ b_dec,
                            float* __restrict__ E, float* __restrict__ D) {
  __shared__ float Xs[8 * 512];
  const int bid = blockIdx.x, t = threadIdx.x;
  const float *X, *Wt, *bias;
  float* out;
  int m0;
  if (bid < 128) { X = enc; Wt = WencT; bias = b_enc; out = E; m0 = bid * 8; }
  else { X = dec; Wt = WdecT; bias = b_dec; out = D; m0 = (bid - 128) * 8; }

#pragma unroll
  for (int i = 0; i < 4; ++i) {
    int f = (i * 256 + t) * 4;
    *(float4*)&Xs[f] = *(const float4*)&X[m0 * 512 + f];
  }
  __syncthreads();

  const int tn = t & 127, tm = t >> 7;  // n = 4*tn, rows m0 + tm*4 + i
  float acc[4][4];
#pragma unroll
  for (int i = 0; i < 4; ++i)
#pragma unroll
    for (int j = 0; j < 4; ++j) acc[i][j] = 0.f;

  for (int k0 = 0; k0 < 512; k0 += 4) {
    float4 xv[4];
#pragma unroll
    for (int i = 0; i < 4; ++i)
      xv[i] = *(const float4*)&Xs[(tm * 4 + i) * 512 + k0];
#pragma unroll
    for (int kk = 0; kk < 4; ++kk) {
      float4 wv = *(const float4*)&Wt[(k0 + kk) * 512 + tn * 4];
#pragma unroll
      for (int i = 0; i < 4; ++i) {
        float x = ((const float*)&xv[i])[kk];
        acc[i][0] += x * wv.x;
        acc[i][1] += x * wv.y;
        acc[i][2] += x * wv.z;
        acc[i][3] += x * wv.w;
      }
    }
  }
  float4 bv = *(const float4*)&bias[tn * 4];
#pragma unroll
  for (int i = 0; i < 4; ++i) {
    float4 o;
    o.x = acc[i][0] + bv.x; o.y = acc[i][1] + bv.y;
    o.z = acc[i][2] + bv.z; o.w = acc[i][3] + bv.w;
    *(float4*)&out[(m0 + tm * 4 + i) * 512 + tn * 4] = o;
  }
}

// ---------------------------------------------------------------- main ------
// One block per (b,t). J-panel tanh(E_row + D[b]) as bf16 [128][520] in LDS.
// 4 N-iters of 256 cols; per wave: 128m x 64n tile = 8x4 frags of 16x16x32.
// W staged per BK=32 via register prefetch -> single LDS buffer [256][40].
__global__ __launch_bounds__(256, 1) void joint_kernel(
    const float* __restrict__ E, const float* __restrict__ D,
    const unsigned short* __restrict__ Wjb, const float* __restrict__ b_joint,
    float* __restrict__ out) {
  __shared__ __align__(16) unsigned short Jlds[128 * 520];  // 130 KB, pad 512->520 (16B-aligned rows, conflict-free b128)
  __shared__ __align__(16) unsigned short Wlds[256 * 40];   // 20 KB,  pad 32->40

  const int t = threadIdx.x;
  const int bt = blockIdx.x;          // b*256 + t_idx
  const int b = bt >> 8;
  const int lane = t & 63;
  const int w = t >> 6;               // wave id: n-range w*64
  const int quad = lane >> 4;
  const int ln15 = lane & 15;

  const float* Dbase = D + (size_t)(b * 128) * 512;
  const float* Erow = E + (size_t)bt * 512;

  // ---- build J panel: 8192 chunks of 8 h-elements; wave-linear LDS writes
  for (int it = 0; it < 32; ++it) {
    int idx = it * 256 + t;
    int u = idx >> 6, c = idx & 63;
    const float* dp = Dbase + u * 512 + c * 8;
    float4 d0 = *(const float4*)dp;
    float4 d1 = *(const float4*)(dp + 4);
    float4 e0 = *(const float4*)(Erow + c * 8);
    float4 e1 = *(const float4*)(Erow + c * 8 + 4);
    ushort8v v;
    v[0] = f2bf(fast_tanh(e0.x + d0.x));
    v[1] = f2bf(fast_tanh(e0.y + d0.y));
    v[2] = f2bf(fast_tanh(e0.z + d0.z));
    v[3] = f2bf(fast_tanh(e0.w + d0.w));
    v[4] = f2bf(fast_tanh(e1.x + d1.x));
    v[5] = f2bf(fast_tanh(e1.y + d1.y));
    v[6] = f2bf(fast_tanh(e1.z + d1.z));
    v[7] = f2bf(fast_tanh(e1.w + d1.w));
    *(ushort8v*)&Jlds[u * 520 + c * 8] = v;
  }

  // ---- prefetch first W tile (ni=0, k0=0): 256 rows x 32 k, 16B/chunk
  uint4 pre[4];
#pragma unroll
  for (int i = 0; i < 4; ++i) {
    int cch = i * 256 + t;
    int row = cch >> 2, cc = cch & 3;
    pre[i] = *(const uint4*)&Wjb[row * 512 + cc * 8];
  }

#pragma unroll 1
  for (int ni = 0; ni < 4; ++ni) {
    const int n0 = ni * 256;
    floatx4 acc[8][4];
#pragma unroll
    for (int mf = 0; mf < 8; ++mf)
#pragma unroll
      for (int nf = 0; nf < 4; ++nf)
        acc[mf][nf] = (floatx4){0.f, 0.f, 0.f, 0.f};
    float bj[4];
#pragma unroll
    for (int nf = 0; nf < 4; ++nf)
      bj[nf] = b_joint[n0 + w * 64 + nf * 16 + ln15];

#pragma unroll 1
    for (int ks = 0; ks < 16; ++ks) {
      const int k0 = ks * 32;
      __syncthreads();  // prior step's b-frag reads done
#pragma unroll
      for (int i = 0; i < 4; ++i) {
        int cch = i * 256 + t;
        int row = cch >> 2, cc = cch & 3;
        *(uint4*)&Wlds[row * 40 + cc * 8] = pre[i];
      }
      __syncthreads();
      // prefetch next tile into regs (in flight under the MFMAs below)
      int nks = ks + 1, nni = ni;
      if (nks == 16) { nks = 0; ++nni; }
      if (nni < 4) {
        const int nk0 = nks * 32, nn0 = nni * 256;
#pragma unroll
        for (int i = 0; i < 4; ++i) {
          int cch = i * 256 + t;
          int row = cch >> 2, cc = cch & 3;
          pre[i] = *(const uint4*)&Wjb[(nn0 + row) * 512 + nk0 + cc * 8];
        }
      }
      // fragments: A[m=ln15][k=quad*8+j], B[k=quad*8+j][n=ln15]
      bf16x8 af[8], bfr[4];
#pragma unroll
      for (int mf = 0; mf < 8; ++mf)
        af[mf] = *(const bf16x8*)&Jlds[(mf * 16 + ln15) * 520 + k0 + quad * 8];
#pragma unroll
      for (int nf = 0; nf < 4; ++nf)
        bfr[nf] = *(const bf16x8*)&Wlds[(w * 64 + nf * 16 + ln15) * 40 + quad * 8];
#pragma unroll
      for (int mf = 0; mf < 8; ++mf)
#pragma unroll
        for (int nf = 0; nf < 4; ++nf)
          acc[mf][nf] = __builtin_amdgcn_mfma_f32_16x16x32_bf16(
              af[mf], bfr[nf], acc[mf][nf], 0, 0, 0);
    }

    // epilogue: D[row=quad*4+r][col=ln15] per frag; add bias; scalar stores
    float* obase = out + (size_t)bt * (128 * 1024) + n0 + w * 64;
#pragma unroll
    for (int mf = 0; mf < 8; ++mf) {
#pragma unroll
      for (int r = 0; r < 4; ++r) {
        int m = mf * 16 + quad * 4 + r;
        float* orow = obase + (size_t)m * 1024;
#pragma unroll
        for (int nf = 0; nf < 4; ++nf)
          orow[nf * 16 + ln15] = acc[mf][nf][r] + bj[nf];
      }
    }
  }
}

extern "C" void kernel_launch(void* const* d_in, const int* in_sizes, int n_in,
                              void* d_out, int out_size, void* d_ws, size_t ws_size,
                              hipStream_t stream) {
  const float* enc_out = (const float*)d_in[0];
  const float* dec_out = (const float*)d_in[1];
  const float* W_enc   = (const float*)d_in[2];
  const float* b_enc   = (const float*)d_in[3];
  const float* W_dec   = (const float*)d_in[4];
  const float* b_dec   = (const float*)d_in[5];
  const float* W_joint = (const float*)d_in[6];
  const float* b_joint = (const float*)d_in[7];
  float* out = (float*)d_out;

  char* ws = (char*)d_ws;  // needs 6 MB
  float* WencT = (float*)(ws);
  float* WdecT = (float*)(ws + (1u << 20));
  unsigned short* Wjb = (unsigned short*)(ws + (2u << 20));
  float* E = (float*)(ws + (3u << 20));
  float* Dm = (float*)(ws + (5u << 20));

  prep_kernel<<<1024, 256, 0, stream>>>(W_enc, W_dec, W_joint, WencT, WdecT, Wjb);
  proj_kernel<<<192, 256, 0, stream>>>(enc_out, dec_out, WencT, WdecT, b_enc, b_dec, E, Dm);
  joint_kernel<<<1024, 256, 0, stream>>>(E, Dm, Wjb, b_joint, out);
}